// Round 12
// baseline (187.162 us; speedup 1.0000x reference)
//
#include <hip/hip_runtime.h>
#include <hip/hip_bf16.h>

constexpr int kB = 16;
constexpr int kN = 2048;
constexpr int kH = 64;
constexpr int kF = 6;

typedef short s16x8 __attribute__((ext_vector_type(8)));
typedef float f32x4 __attribute__((ext_vector_type(4)));

__device__ __forceinline__ unsigned short f2bf(float f) {
  __hip_bfloat16 h = __float2bfloat16(f);
  unsigned short u;
  __builtin_memcpy(&u, &h, 2);
  return u;
}

__device__ __forceinline__ float bf2f(unsigned short u) {
  unsigned int b = ((unsigned int)u) << 16;
  float f;
  __builtin_memcpy(&f, &b, 4);
  return f;
}

__device__ __forceinline__ float eluf(float x) {
  return x > 0.0f ? x : __expf(x) - 1.0f;
}

__device__ __forceinline__ unsigned int pack8(uint4 a, uint4 b) {
  unsigned int t1 = (a.y << 1) + a.x;
  unsigned int t2 = (a.w << 1) + a.z;
  unsigned int n0 = (t2 << 2) + t1;
  unsigned int u1 = (b.y << 1) + b.x;
  unsigned int u2 = (b.w << 1) + b.z;
  unsigned int n1 = (u2 << 2) + u1;
  return (n1 << 4) + n0;
}

// ---------------------------------------------------------------- layer1 embed
// Also: block 0 zeroes sumh; block 1 precomputes W2^T as bf16 hi/lo into ws.
__global__ __launch_bounds__(256) void k_embed(
    const float* __restrict__ x, const float* __restrict__ W,
    const float* __restrict__ asrc, const float* __restrict__ adst,
    const float* __restrict__ mask,
    float* __restrict__ hf, unsigned short* __restrict__ hT,
    unsigned int* __restrict__ uvpk, float* __restrict__ Rr,
    float* __restrict__ sumh,
    const float* __restrict__ W2,
    unsigned short* __restrict__ w2thi, unsigned short* __restrict__ w2tlo) {
  __shared__ float lh[64][65];
  __shared__ float psd[2][4][64];
  const int r0 = blockIdx.x * 64;
  const int b = r0 >> 11;
  const int i0 = r0 & (kN - 1);
  const int t = threadIdx.x;
  const int k = t & 63;
  const int w = t >> 6;
  if (blockIdx.x == 0) {
#pragma unroll
    for (int i = 0; i < 4; ++i) sumh[t + 256 * i] = 0.0f;
  }
  if (blockIdx.x == 1) {
#pragma unroll
    for (int i = 0; i < 16; ++i) {
      const int idx = t + 256 * i;  // 4096 = 64x64
      const int col = idx & 63, kk = idx >> 6;
      const float wv = W2[kk * kH + col];
      const unsigned short hh = f2bf(wv);
      w2thi[col * 64 + kk] = hh;
      w2tlo[col * 64 + kk] = f2bf(wv - bf2f(hh));
    }
  }
  for (int it = 0; it < 16; ++it) {
    const int rl = w * 16 + it;
    const int row = r0 + rl;
    float h = 0.0f;
#pragma unroll
    for (int f = 0; f < kF; ++f) h = fmaf(x[(size_t)row * kF + f], W[f * kH + k], h);
    lh[rl][k] = h;
    hf[(size_t)row * kH + k] = h;
  }
  __syncthreads();
  float sp = 0.0f, dp = 0.0f;
#pragma unroll
  for (int kk = 0; kk < 16; ++kk) {
    const int k2 = w * 16 + kk;
    const float hv = lh[k][k2];
    sp = fmaf(hv, asrc[k2], sp);
    dp = fmaf(hv, adst[k2], dp);
  }
  psd[0][w][k] = sp;
  psd[1][w][k] = dp;
  __syncthreads();
  if (t < 64) {
    const float s = psd[0][0][t] + psd[0][1][t] + psd[0][2][t] + psd[0][3][t];
    const float d = psd[1][0][t] + psd[1][1][t] + psd[1][2][t] + psd[1][3][t];
    const int row = r0 + t;
    const bool mv = mask[row] != 0.0f;
    const float u = mv ? __expf(d) : 0.0f;
    const float v = mv ? __expf(0.2f * d) : 0.0f;
    uvpk[row] = ((unsigned int)f2bf(u) << 16) | f2bf(v);
    Rr[row] = __expf(-0.8f * s);
  }
  const size_t tb = (size_t)b * kN * kH + (size_t)(i0 >> 5) * 2048;
  for (int it = 0; it < 16; ++it) {
    const int kk = w * 16 + it;
    hT[tb + (size_t)(k >> 5) * 2048 + kk * 32 + (k & 31)] = f2bf(lh[k][kk]);
  }
}

// ---------------------------------------------------------------- fused GAT attention
// Block = 64 full rows, 512 threads, 8 waves: (row-tile rt = wv>>1, 0..3) x
// (chunk parity hf2 = wv&1). Per iteration jt, wave (rt,hf2) consumes chunk
// 2*jt+hf2 (32 cols) for rows rt*16..+16. Verified structure: hT register
// prefetch -> LDS publish double-buffer; raw s_barrier + lgkmcnt(0) only (T4);
// mask-derived loop truncation (ntj) + row-skip (bit-exact).
// LDS f-tile j-stride padded 32 -> 36 shorts. Unpadded, the B-fragment
// ds_read_b128 (lane byte addr r*64+g*16) put even-r lanes at bank 0 and
// odd-r at bank 16 -> 4-8-way conflict on every f read (R5 counters: 2.57M
// SQ_LDS_BANK_CONFLICT). Padded stride 36 gives bank-start (r*18+g*4)%32
// -> all 16 lanes distinct, <=2-way (free). Publish/stage writes use the
// remapped index (t>>8)*2304 + ((t>>6)&3)*576 + ((t>>2)&15)*36 + (t&3)*8.
// Global hT layout unchanged.
// EMB: epilogue computes the full layer-2 embed for this block's 64 rows.
// NOTE epilogue ordering: lhFF[64][65] f32 (16640B at smem+0) overlaps uvl and
// the start of blw -> the PACK bits dump (reads blw) MUST precede lhFF writes.
template <bool PACK, bool TAIL, bool EMB>
__global__ __launch_bounds__(512) void k_attn(
    const int* __restrict__ adj, unsigned int* __restrict__ bits,
    const unsigned short* __restrict__ hT,
    const unsigned int* __restrict__ uvpk, const float* __restrict__ Rr,
    const float* __restrict__ hres, const float* __restrict__ mask,
    const float* __restrict__ aw1, const float* __restrict__ ab1,
    const float* __restrict__ aw2, const float* __restrict__ ab2,
    float* __restrict__ logits, float* __restrict__ sumh,
    const unsigned short* __restrict__ w2thi, const unsigned short* __restrict__ w2tlo,
    const float* __restrict__ asrc2, const float* __restrict__ adst2,
    float* __restrict__ h2res, unsigned short* __restrict__ hT2,
    unsigned int* __restrict__ uv2, float* __restrict__ Rr2) {
  // layout: uvl@0 (8192) | blw@8192 ([64][65] words, 16640) | hbase@24832
  //   (2 pair-bufs x 4608 shorts = 18432B -> ends 43264)
  // epilogue reuse: psumF@24832 ([64][66] f32, 16896) zsumF@41728 (256)
  //                 csF@41984 ([8][64] f32, 2048); lhFF@0 ([64][65] f32, 16640)
  __shared__ __align__(16) char smem[44032];
  unsigned int* uvl = (unsigned int*)smem;
  unsigned int* blw = (unsigned int*)(smem + 8192);
  unsigned short* hbase = (unsigned short*)(smem + 24832);
  // blw padding words (index % 65 == 64) are untouched by all loop traffic:
  int* mxp = (int*)&blw[64];    // max nonzero uv word index
  int* rfp = (int*)&blw[129];   // row-active flag

  const int bid0 = blockIdx.x;
  const int swz = (bid0 & 7) * 64 + (bid0 >> 3);  // 512 blocks: 2 batches per XCD
  const int b = swz >> 5;
  const int rb = swz & 31;
  const int row0 = rb * 64;

  const int t = threadIdx.x;   // 0..511
  const int wv = t >> 6;       // 0..7
  const int l = t & 63;
  const int r = l & 15;
  const int g = l >> 4;
  const int hf2 = wv & 1;
  const int rt = wv >> 1;      // 0..3
  const int rloc = rt * 16 + r;

  if (t == 0) { *mxp = -1; *rfp = 0; }

  // padded LDS index (shorts) for thread t's 16B chunk of an 8KB tile-pair:
  // tile = t>>8, hg = (t>>6)&3, h = (t>>2)&15, jq = t&3
  const int pi = (t >> 8) * 2304 + ((t >> 6) & 3) * 576 + ((t >> 2) & 15) * 36 + (t & 3) * 8;

  // stage uv (full row, 8KB; 512 x 16B)
  {
    const uint4* src = (const uint4*)(uvpk + (size_t)b * kN);
    ((uint4*)uvl)[t] = src[t];
  }

  // hT staging: thread t owns bytes [t*16, t*16+16) of each 8KB tile-PAIR.
  // Pair 0 (tiles 0,1) -> buf0 (padded); regs hc0 = pair 1 (tiles 2,3, raw).
  const unsigned short* hTb = hT + (size_t)b * kN * kH;
  const char* hTc = (const char*)hTb;
  *(uint4*)(hbase + pi) = *(const uint4*)(hTc + t * 16);
  uint4 hc0 = *(const uint4*)(hTc + 8192 + t * 16);
  uint4 hn0 = {};

  // bits: PACK = JIT from adj; packer lane (brow 0..63, bh, bq4) covers word
  // 2*it + bh, byte bq4 of its row. else: stage all from global.
  const int brow = t >> 3;
  const int bc = t & 7;
  const int bh = bc >> 2;
  const int bq4 = bc & 3;
  const int* adjLp = adj + ((size_t)b * kN + row0 + brow) * kN + bh * 32 + bq4 * 8;
  uint4 qcA = {}, qcB = {}, qnA = {}, qnB = {};
  if (PACK) {
    const uint4 a0 = *(const uint4*)(adjLp);
    const uint4 a1 = *(const uint4*)(adjLp + 4);
    ((unsigned char*)blw)[(brow * 65 + bh) * 4 + bq4] = (unsigned char)pack8(a0, a1);  // words 0,1
    qcA = *(const uint4*)(adjLp + 64);   // words 2,3
    qcB = *(const uint4*)(adjLp + 68);
  } else {
#pragma unroll
    for (int ii = 0; ii < 8; ++ii) {
      const int idx = ii * 512 + t;   // 4096 words
      const int rr2 = idx >> 6, wj = idx & 63;
      blw[rr2 * 65 + wj] = bits[((size_t)b * kN + row0 + rr2) * 64 + wj];
    }
  }

  const float Ri = Rr[(size_t)b * kN + row0 + rloc];
  __syncthreads();

  // data-derived loop bound + row-activity (exact: zero uv word -> afrag = 0)
  {
    int lm = -1;
#pragma unroll
    for (int i = 0; i < 4; ++i)
      if (uvl[t * 4 + i] != 0u) lm = t * 4 + i;
    if (lm >= 0) atomicMax(mxp, lm);
    if (t < 64 && mask[(size_t)b * kN + row0 + t] != 0.0f) atomicOr(rfp, 1);
  }
  __syncthreads();
  const int mxv = *mxp;
  const int ntj = (mxv < 0) ? 0 : ((mxv >> 6) + 1);  // 64 cols per iter
  const bool ract = (*rfp != 0);

  f32x4 acc0 = {0.f, 0.f, 0.f, 0.f}, acc1 = {0.f, 0.f, 0.f, 0.f};
  f32x4 acc2 = {0.f, 0.f, 0.f, 0.f}, acc3 = {0.f, 0.f, 0.f, 0.f};
  f32x4 accz = {0.f, 0.f, 0.f, 0.f};
  s16x8 ones;
#pragma unroll
  for (int e = 0; e < 8; ++e) ones[e] = (r == 0) ? (short)0x3F80 : (short)0;

  if (ract) {
    for (int jt = 0; jt < ntj; ++jt) {
      // issue loads for iter jt+1's publish: tile-pair jt+2; adj words 2jt+4,5
      if (jt < ntj - 2) {
        hn0 = *(const uint4*)(hTc + (size_t)(jt + 2) * 8192 + t * 16);
        if (PACK) {
          qnA = *(const uint4*)(adjLp + (size_t)(jt + 2) * 64);
          qnB = *(const uint4*)(adjLp + (size_t)(jt + 2) * 64 + 4);
        }
      }
      // publish for iter jt+1: tile-pair jt+1 (regs loaded at jt-1); words 2jt+2,3
      if (jt < ntj - 1) {
        *(uint4*)(hbase + ((jt + 1) & 1) * 4608 + pi) = hc0;
        if (PACK)
          ((unsigned char*)blw)[(brow * 65 + 2 * jt + 2 + bh) * 4 + bq4] =
              (unsigned char)pack8(qcA, qcB);
      }

      // consume chunk 2*jt + hf2 for rows rt*16..+16
      const unsigned int bw = blw[rloc * 65 + 2 * jt + hf2];
      const unsigned int byt = (bw >> (g * 8)) & 0xffu;
      const unsigned int* uvp = uvl + (2 * jt + hf2) * 32 + g * 8;
      const uint4 ua = *(const uint4*)uvp;
      const uint4 ub = *(const uint4*)(uvp + 4);
      union { s16x8 v; unsigned int w[4]; } afu;
      {
        const unsigned int uvw[8] = {ua.x, ua.y, ua.z, ua.w, ub.x, ub.y, ub.z, ub.w};
#pragma unroll
        for (int p = 0; p < 4; ++p) {
          unsigned int ulb = uvw[2 * p] & 0xFFFF0000u, vlb = uvw[2 * p] << 16;
          unsigned int uhb = uvw[2 * p + 1] & 0xFFFF0000u, vhb = uvw[2 * p + 1] << 16;
          float ulf, vlf, uhf, vhf;
          __builtin_memcpy(&ulf, &ulb, 4); __builtin_memcpy(&vlf, &vlb, 4);
          __builtin_memcpy(&uhf, &uhb, 4); __builtin_memcpy(&vhf, &vhb, 4);
          const float vall = fmaxf(ulf, Ri * vlf);
          const float valh = fmaxf(uhf, Ri * vhf);
          unsigned int lbits, hbits;
          __builtin_memcpy(&lbits, &vall, 4); __builtin_memcpy(&hbits, &valh, 4);
          lbits = (byt & (1u << (2 * p))) ? lbits : 0u;
          hbits = (byt & (1u << (2 * p + 1))) ? hbits : 0u;
          afu.w[p] = (hbits & 0xFFFF0000u) | (lbits >> 16);
        }
      }
      // padded f reads: tile stride 2304, hg stride 576, row stride 36
      const unsigned short* cur = hbase + ((jt & 1) * 2 + hf2) * 2304 + r * 36 + g * 8;
      const s16x8 f0 = *(const s16x8*)(cur);
      const s16x8 f1 = *(const s16x8*)(cur + 576);
      const s16x8 f2 = *(const s16x8*)(cur + 1152);
      const s16x8 f3 = *(const s16x8*)(cur + 1728);

      acc0 = __builtin_amdgcn_mfma_f32_16x16x32_bf16(afu.v, f0, acc0, 0, 0, 0);
      acc1 = __builtin_amdgcn_mfma_f32_16x16x32_bf16(afu.v, f1, acc1, 0, 0, 0);
      acc2 = __builtin_amdgcn_mfma_f32_16x16x32_bf16(afu.v, f2, acc2, 0, 0, 0);
      acc3 = __builtin_amdgcn_mfma_f32_16x16x32_bf16(afu.v, f3, acc3, 0, 0, 0);
      accz = __builtin_amdgcn_mfma_f32_16x16x32_bf16(afu.v, ones, accz, 0, 0, 0);

      // raw barrier: wait LDS ops only; global prefetch stays in flight (T4)
      asm volatile("s_waitcnt lgkmcnt(0)" ::: "memory");
      __builtin_amdgcn_s_barrier();
      hc0 = hn0;
      if (PACK) { qcA = qnA; qcB = qnB; }
    }
  }

  // ---- epilogue: in-block combine of the two chunk-parity halves ----
  float* psumF = (float*)(smem + 24832);          // [64][66]
  float* zsumF = (float*)(smem + 41728);          // [64]
  if (hf2 == 1) {
#pragma unroll
    for (int q = 0; q < 4; ++q) {
      const int lrow = rt * 16 + g * 4 + q;
      psumF[lrow * 66 + r + 0]  = acc0[q];
      psumF[lrow * 66 + r + 16] = acc1[q];
      psumF[lrow * 66 + r + 32] = acc2[q];
      psumF[lrow * 66 + r + 48] = acc3[q];
      if (r == 0) zsumF[lrow] = accz[q];
    }
  }
  // PACK bits write-out MUST precede lhFF writes (lhFF overlaps uvl+blw start).
  if (PACK) {
#pragma unroll
    for (int ii = 0; ii < 8; ++ii) {
      const int idx = ii * 512 + t;
      const int rr2 = idx >> 6, wj = idx & 63;
      bits[((size_t)b * kN + row0 + rr2) * 64 + wj] = blw[rr2 * 65 + wj];
    }
  }
  __syncthreads();
  float* lhFF = (float*)smem;  // final h-layer rows [64][65] (TAIL and EMB)
  if (hf2 == 0) {
#pragma unroll
    for (int q = 0; q < 4; ++q) {
      const int lrow = rt * 16 + g * 4 + q;
      const float zq = __shfl(accz[q], (l & 48)) + zsumF[lrow];
      const float inv = (zq > 0.0f) ? 1.0f / zq : 0.0f;
      const size_t rowg = (size_t)b * kN + row0 + lrow;
      const float mk = mask[rowg];
      const float* hrp = hres + rowg * kH;
      const float o0 = eluf(fmaf(acc0[q] + psumF[lrow * 66 + r + 0],  inv, hrp[r + 0]))  * mk;
      const float o1 = eluf(fmaf(acc1[q] + psumF[lrow * 66 + r + 16], inv, hrp[r + 16])) * mk;
      const float o2 = eluf(fmaf(acc2[q] + psumF[lrow * 66 + r + 32], inv, hrp[r + 32])) * mk;
      const float o3 = eluf(fmaf(acc3[q] + psumF[lrow * 66 + r + 48], inv, hrp[r + 48])) * mk;
      lhFF[lrow * 65 + r + 0]  = o0;
      lhFF[lrow * 65 + r + 16] = o1;
      lhFF[lrow * 65 + r + 32] = o2;
      lhFF[lrow * 65 + r + 48] = o3;
    }
  }

  if (EMB) {
    // layer-2 embed for this block's 64 rows: h2 = lhFF(64x64) @ W2(64x64).
    // Wave (rt,hf2): rows rt*16..+16, cols hf2*32..+32 (ntb = hf2*2, +1).
    __syncthreads();
    const int ntb = hf2 * 2;
    s16x8 ah[2], al[2];
    {
      const float* arow = lhFF + (rt * 16 + r) * 65;
#pragma unroll
      for (int ks = 0; ks < 2; ++ks) {
#pragma unroll
        for (int j = 0; j < 8; ++j) {
          const float v = arow[ks * 32 + g * 8 + j];
          const unsigned short hh = f2bf(v);
          ah[ks][j] = (short)hh;
          al[ks][j] = (short)f2bf(v - bf2f(hh));
        }
      }
    }
    f32x4 e0 = {0.f, 0.f, 0.f, 0.f}, e1 = {0.f, 0.f, 0.f, 0.f};
#pragma unroll
    for (int ks = 0; ks < 2; ++ks) {
      const int kof = ks * 32 + g * 8;
      {
        const s16x8 bhi = *(const s16x8*)(w2thi + (ntb * 16 + r) * 64 + kof);
        const s16x8 blo = *(const s16x8*)(w2tlo + (ntb * 16 + r) * 64 + kof);
        e0 = __builtin_amdgcn_mfma_f32_16x16x32_bf16(ah[ks], bhi, e0, 0, 0, 0);
        e0 = __builtin_amdgcn_mfma_f32_16x16x32_bf16(al[ks], bhi, e0, 0, 0, 0);
        e0 = __builtin_amdgcn_mfma_f32_16x16x32_bf16(ah[ks], blo, e0, 0, 0, 0);
      }
      {
        const s16x8 bhi = *(const s16x8*)(w2thi + ((ntb + 1) * 16 + r) * 64 + kof);
        const s16x8 blo = *(const s16x8*)(w2tlo + ((ntb + 1) * 16 + r) * 64 + kof);
        e1 = __builtin_amdgcn_mfma_f32_16x16x32_bf16(ah[ks], bhi, e1, 0, 0, 0);
        e1 = __builtin_amdgcn_mfma_f32_16x16x32_bf16(al[ks], bhi, e1, 0, 0, 0);
        e1 = __builtin_amdgcn_mfma_f32_16x16x32_bf16(ah[ks], blo, e1, 0, 0, 0);
      }
    }
    float* lh2F = (float*)(smem + 24832);  // [64][66], reuse psum area
#pragma unroll
    for (int q = 0; q < 4; ++q) {
      const int lrow = rt * 16 + g * 4 + q;
      lh2F[lrow * 66 + ntb * 16 + r] = e0[q];
      lh2F[lrow * 66 + (ntb + 1) * 16 + r] = e1[q];
      const size_t rowg = (size_t)b * kN + row0 + lrow;
      h2res[rowg * kH + ntb * 16 + r] = e0[q];
      h2res[rowg * kH + (ntb + 1) * 16 + r] = e1[q];
    }
    __syncthreads();
    // hT2: 2 chunks (rb*2, rb*2+1), [chunk][col][row32]
    {
      const int ch = t >> 8;          // 0,1
      const int tt = t & 255;
      const int kr = tt & 31, wc = tt >> 5;
      const size_t tb2 = (size_t)b * kN * kH + (size_t)(rb * 2 + ch) * 2048;
#pragma unroll
      for (int it = 0; it < 8; ++it) {
        const int c = wc * 8 + it;
        hT2[tb2 + c * 32 + kr] = f2bf(lh2F[(ch * 32 + kr) * 66 + c]);
      }
    }
    // uvpk2 / Rr2: per row dot with asrc2/adst2 (8 lanes per row, 64 rows)
    {
      const int rw = t >> 3, c0 = (t & 7) * 8;
      float sp = 0.0f, dp = 0.0f;
#pragma unroll
      for (int j = 0; j < 8; ++j) {
        const float hv = lh2F[rw * 66 + c0 + j];
        sp = fmaf(hv, asrc2[c0 + j], sp);
        dp = fmaf(hv, adst2[c0 + j], dp);
      }
#pragma unroll
      for (int o = 4; o; o >>= 1) {
        sp += __shfl_xor(sp, o);
        dp += __shfl_xor(dp, o);
      }
      if ((t & 7) == 0) {
        const size_t rowg = (size_t)b * kN + row0 + rw;
        const bool mv = mask[rowg] != 0.0f;
        const float u = mv ? __expf(dp) : 0.0f;
        const float v = mv ? __expf(0.2f * dp) : 0.0f;
        uv2[rowg] = ((unsigned int)f2bf(u) << 16) | f2bf(v);
        Rr2[rowg] = __expf(-0.8f * sp);
      }
    }
  }

  if (TAIL) {
    __syncthreads();
    const int ln = t & 31;
    const int grp = t >> 5;   // 0..15, 4 rows each = 64
#pragma unroll
    for (int rr2 = 0; rr2 < 4; ++rr2) {
      const int lrow = grp * 4 + rr2;
      float accA = ab1[ln];
#pragma unroll 8
      for (int m = 0; m < kH; ++m) accA = fmaf(lhFF[lrow * 65 + m], aw1[m * 32 + ln], accA);
      float p = eluf(accA) * aw2[ln];
#pragma unroll
      for (int o = 16; o; o >>= 1) p += __shfl_xor(p, o, 32);
      if (ln == 0) logits[(size_t)b * kN + row0 + lrow] = p + ab2[0];
    }
    float cs = 0.0f;
    const int kcol = t & 63;
    const int seg = t >> 6;   // 0..7, 8 rows each
#pragma unroll
    for (int ii = 0; ii < 8; ++ii) cs += lhFF[(seg * 8 + ii) * 65 + kcol];
    float* csF = (float*)(smem + 41984);   // [8][64]
    csF[seg * 64 + kcol] = cs;
    __syncthreads();
    if (t < 64) {
      float s = 0.0f;
#pragma unroll
      for (int k2 = 0; k2 < 8; ++k2) s += csF[k2 * 64 + t];
      atomicAdd(&sumh[b * 64 + t], s);
    }
  }
}

// ---------------------------------------------------------------- critic head
__global__ __launch_bounds__(64) void k_critic2(
    const float* __restrict__ sumh, const float* __restrict__ mask,
    const float* __restrict__ cw1, const float* __restrict__ cb1,
    const float* __restrict__ cw2, const float* __restrict__ cb2,
    float* __restrict__ value) {
  __shared__ float lgh[64];
  const int b = blockIdx.x, t = threadIdx.x;
  float c = 0.0f;
#pragma unroll
  for (int ii = 0; ii < 32; ++ii) c += mask[(size_t)b * kN + t + 64 * ii];
#pragma unroll
  for (int off = 32; off; off >>= 1) c += __shfl_xor(c, off);
  lgh[t] = sumh[b * 64 + t] / fmaxf(c, 1.0f);
  __syncthreads();
  if (t < 32) {
    float acc = cb1[t];
#pragma unroll 8
    for (int m = 0; m < kH; ++m) acc = fmaf(lgh[m], cw1[m * 32 + t], acc);
    float p = eluf(acc) * cw2[t];
#pragma unroll
    for (int off = 16; off; off >>= 1) p += __shfl_xor(p, off, 32);
    if (t == 0) value[b] = p + cb2[0];
  }
}

// ----------------------------------------------------------------
extern "C" void kernel_launch(void* const* d_in, const int* in_sizes, int n_in,
                              void* d_out, int out_size, void* d_ws, size_t ws_size,
                              hipStream_t stream) {
  const float* x = (const float*)d_in[0];
  const int* adj = (const int*)d_in[1];
  const float* mask = (const float*)d_in[2];
  const float* W1 = (const float*)d_in[3];
  const float* asrc1 = (const float*)d_in[4];
  const float* adst1 = (const float*)d_in[5];
  const float* W2 = (const float*)d_in[6];
  const float* asrc2 = (const float*)d_in[7];
  const float* adst2 = (const float*)d_in[8];
  const float* aw1 = (const float*)d_in[9];
  const float* ab1 = (const float*)d_in[10];
  const float* aw2 = (const float*)d_in[11];
  const float* ab2 = (const float*)d_in[12];
  const float* cw1 = (const float*)d_in[13];
  const float* cb1 = (const float*)d_in[14];
  const float* cw2 = (const float*)d_in[15];
  const float* cb2 = (const float*)d_in[16];
  float* logits = (float*)d_out;
  float* value = (float*)d_out + kB * kN;

  char* ws = (char*)d_ws;
  size_t off = 0;
  auto take = [&](size_t bytes) {
    char* p = ws + off;
    off = (off + bytes + 255) & ~(size_t)255;
    return p;
  };
  unsigned int* bits = (unsigned int*)take((size_t)kB * kN * (kN / 8));
  float* hA = (float*)take((size_t)kB * kN * kH * 4);    // layer1 embed h (residual 1)
  float* hA2 = (float*)take((size_t)kB * kN * kH * 4);   // layer2 embed h (residual 2)
  unsigned short* hT1 = (unsigned short*)take((size_t)kB * kN * kH * 2);
  unsigned short* hT2 = (unsigned short*)take((size_t)kB * kN * kH * 2);
  unsigned int* uv1 = (unsigned int*)take((size_t)kB * kN * 4);
  unsigned int* uv2 = (unsigned int*)take((size_t)kB * kN * 4);
  float* R1 = (float*)take((size_t)kB * kN * 4);
  float* R2 = (float*)take((size_t)kB * kN * 4);
  float* sumh = (float*)take(kB * kH * 4);
  unsigned short* w2thi = (unsigned short*)take(64 * 64 * 2);
  unsigned short* w2tlo = (unsigned short*)take(64 * 64 * 2);

  // layer 1 embed (+ sumh zero, W2^T bf16 precompute)
  k_embed<<<kB * kN / 64, 256, 0, stream>>>(x, W1, asrc1, adst1, mask, hA, hT1, uv1, R1,
                                            sumh, W2, w2thi, w2tlo);
  // layer 1 attn, fused with layer 2 embed (writes hA2/hT2/uv2/R2; JIT-packs adj -> bits)
  k_attn<true, false, true><<<kB * 32, 512, 0, stream>>>(
      adj, bits, hT1, uv1, R1, hA, mask, aw1, ab1, aw2, ab2, logits, sumh,
      w2thi, w2tlo, asrc2, adst2, hA2, hT2, uv2, R2);
  // layer 2 attn, tail-fused (actor head + column sums)
  k_attn<false, true, false><<<kB * 32, 512, 0, stream>>>(
      adj, bits, hT2, uv2, R2, hA2, mask, aw1, ab1, aw2, ab2, logits, sumh,
      nullptr, nullptr, nullptr, nullptr, nullptr, nullptr, nullptr, nullptr);
  // critic
  k_critic2<<<kB, 64, 0, stream>>>(sumh, mask, cw1, cb1, cw2, cb2, value);
}

// Round 13
// 110.373 us; speedup vs baseline: 1.6957x; 1.6957x over previous
//
#include <hip/hip_runtime.h>
#include <hip/hip_bf16.h>

constexpr int kB = 16;
constexpr int kN = 2048;
constexpr int kH = 64;
constexpr int kF = 6;

typedef short s16x8 __attribute__((ext_vector_type(8)));
typedef float f32x4 __attribute__((ext_vector_type(4)));

__device__ __forceinline__ unsigned short f2bf(float f) {
  __hip_bfloat16 h = __float2bfloat16(f);
  unsigned short u;
  __builtin_memcpy(&u, &h, 2);
  return u;
}

__device__ __forceinline__ float bf2f(unsigned short u) {
  unsigned int b = ((unsigned int)u) << 16;
  float f;
  __builtin_memcpy(&f, &b, 4);
  return f;
}

__device__ __forceinline__ float eluf(float x) {
  return x > 0.0f ? x : __expf(x) - 1.0f;
}

__device__ __forceinline__ unsigned int pack8(uint4 a, uint4 b) {
  unsigned int t1 = (a.y << 1) + a.x;
  unsigned int t2 = (a.w << 1) + a.z;
  unsigned int n0 = (t2 << 2) + t1;
  unsigned int u1 = (b.y << 1) + b.x;
  unsigned int u2 = (b.w << 1) + b.z;
  unsigned int n1 = (u2 << 2) + u1;
  return (n1 << 4) + n0;
}

// ---------------------------------------------------------------- layer1 embed
// Also: block 0 zeroes sumh; block 1 precomputes W2^T as bf16 hi/lo into ws.
__global__ __launch_bounds__(256) void k_embed(
    const float* __restrict__ x, const float* __restrict__ W,
    const float* __restrict__ asrc, const float* __restrict__ adst,
    const float* __restrict__ mask,
    float* __restrict__ hf, unsigned short* __restrict__ hT,
    unsigned int* __restrict__ uvpk, float* __restrict__ Rr,
    float* __restrict__ sumh,
    const float* __restrict__ W2,
    unsigned short* __restrict__ w2thi, unsigned short* __restrict__ w2tlo) {
  __shared__ float lh[64][65];
  __shared__ float psd[2][4][64];
  const int r0 = blockIdx.x * 64;
  const int b = r0 >> 11;
  const int i0 = r0 & (kN - 1);
  const int t = threadIdx.x;
  const int k = t & 63;
  const int w = t >> 6;
  if (blockIdx.x == 0) {
#pragma unroll
    for (int i = 0; i < 4; ++i) sumh[t + 256 * i] = 0.0f;
  }
  if (blockIdx.x == 1) {
#pragma unroll
    for (int i = 0; i < 16; ++i) {
      const int idx = t + 256 * i;  // 4096 = 64x64
      const int col = idx & 63, kk = idx >> 6;
      const float wv = W2[kk * kH + col];
      const unsigned short hh = f2bf(wv);
      w2thi[col * 64 + kk] = hh;
      w2tlo[col * 64 + kk] = f2bf(wv - bf2f(hh));
    }
  }
  for (int it = 0; it < 16; ++it) {
    const int rl = w * 16 + it;
    const int row = r0 + rl;
    float h = 0.0f;
#pragma unroll
    for (int f = 0; f < kF; ++f) h = fmaf(x[(size_t)row * kF + f], W[f * kH + k], h);
    lh[rl][k] = h;
    hf[(size_t)row * kH + k] = h;
  }
  __syncthreads();
  float sp = 0.0f, dp = 0.0f;
#pragma unroll
  for (int kk = 0; kk < 16; ++kk) {
    const int k2 = w * 16 + kk;
    const float hv = lh[k][k2];
    sp = fmaf(hv, asrc[k2], sp);
    dp = fmaf(hv, adst[k2], dp);
  }
  psd[0][w][k] = sp;
  psd[1][w][k] = dp;
  __syncthreads();
  if (t < 64) {
    const float s = psd[0][0][t] + psd[0][1][t] + psd[0][2][t] + psd[0][3][t];
    const float d = psd[1][0][t] + psd[1][1][t] + psd[1][2][t] + psd[1][3][t];
    const int row = r0 + t;
    const bool mv = mask[row] != 0.0f;
    const float u = mv ? __expf(d) : 0.0f;
    const float v = mv ? __expf(0.2f * d) : 0.0f;
    uvpk[row] = ((unsigned int)f2bf(u) << 16) | f2bf(v);
    Rr[row] = __expf(-0.8f * s);
  }
  const size_t tb = (size_t)b * kN * kH + (size_t)(i0 >> 5) * 2048;
  for (int it = 0; it < 16; ++it) {
    const int kk = w * 16 + it;
    hT[tb + (size_t)(k >> 5) * 2048 + kk * 32 + (k & 31)] = f2bf(lh[k][kk]);
  }
}

// ---------------------------------------------------------------- fused GAT attention
// Block = 64 full rows, 512 threads, 8 waves: (row-tile rt = wv>>1, 0..3) x
// (chunk parity hf2 = wv&1). Per iteration jt, wave (rt,hf2) consumes chunk
// 2*jt+hf2 (32 cols) for rows rt*16..+16. Verified structure: hT register
// prefetch -> LDS publish double-buffer; raw s_barrier + lgkmcnt(0) only (T4);
// mask-derived loop truncation (ntj) + row-skip (bit-exact).
// LDS f-tile SLOT ROTATION (alignment-preserving bank fix; R12's +pad broke
// 16B alignment -> 187us): row r's g-th 16B fragment is stored in slot
// s = (g + (r>>1)) & 3 (byte r*64 + s*16). Quarter-wave bank-starts become
// 16(r&1)+4s: each bank covered exactly 2x on reads AND writes = conflict-free
// (2-way aliasing is free, m136). All accesses stay 16B-aligned b128.
// Same formula on publish/stage write and on read (both-sides-or-neither).
// EMB: epilogue computes the full layer-2 embed for this block's 64 rows.
// NOTE epilogue ordering: lhFF[64][65] f32 (16640B at smem+0) overlaps uvl and
// the start of blw -> the PACK bits dump (reads blw) MUST precede lhFF writes.
template <bool PACK, bool TAIL, bool EMB>
__global__ __launch_bounds__(512) void k_attn(
    const int* __restrict__ adj, unsigned int* __restrict__ bits,
    const unsigned short* __restrict__ hT,
    const unsigned int* __restrict__ uvpk, const float* __restrict__ Rr,
    const float* __restrict__ hres, const float* __restrict__ mask,
    const float* __restrict__ aw1, const float* __restrict__ ab1,
    const float* __restrict__ aw2, const float* __restrict__ ab2,
    float* __restrict__ logits, float* __restrict__ sumh,
    const unsigned short* __restrict__ w2thi, const unsigned short* __restrict__ w2tlo,
    const float* __restrict__ asrc2, const float* __restrict__ adst2,
    float* __restrict__ h2res, unsigned short* __restrict__ hT2,
    unsigned int* __restrict__ uv2, float* __restrict__ Rr2) {
  // layout: uvl@0 (8192) | blw@8192 ([64][65] words, 16640) | hbase@24832 (16384)
  // epilogue reuse: psumF@24832 ([64][66] f32, 16896) zsumF@41728 (256)
  //                 csF@41984 ([8][64] f32, 2048); lhFF@0 ([64][65] f32, 16640)
  __shared__ __align__(16) char smem[44032];
  unsigned int* uvl = (unsigned int*)smem;
  unsigned int* blw = (unsigned int*)(smem + 8192);
  unsigned short* hbase = (unsigned short*)(smem + 24832);
  // blw padding words (index % 65 == 64) are untouched by all loop traffic:
  int* mxp = (int*)&blw[64];    // max nonzero uv word index
  int* rfp = (int*)&blw[129];   // row-active flag

  const int bid0 = blockIdx.x;
  const int swz = (bid0 & 7) * 64 + (bid0 >> 3);  // 512 blocks: 2 batches per XCD
  const int b = swz >> 5;
  const int rb = swz & 31;
  const int row0 = rb * 64;

  const int t = threadIdx.x;   // 0..511
  const int wv = t >> 6;       // 0..7
  const int l = t & 63;
  const int r = l & 15;
  const int g = l >> 4;
  const int hf2 = wv & 1;
  const int rt = wv >> 1;      // 0..3
  const int rloc = rt * 16 + r;

  if (t == 0) { *mxp = -1; *rfp = 0; }

  // slot-rotated LDS index (shorts) for thread t's 16B chunk of an 8KB
  // tile-pair: tile=t>>8, hg=(t>>6)&3, row h=(t>>2)&15, slot s=((t&3)+(h>>1))&3
  const int ph = (t >> 2) & 15;
  const int ps = ((t & 3) + (ph >> 1)) & 3;
  const int pi = (t >> 8) * 2048 + ((t >> 6) & 3) * 512 + ph * 32 + ps * 8;

  // stage uv (full row, 8KB; 512 x 16B)
  {
    const uint4* src = (const uint4*)(uvpk + (size_t)b * kN);
    ((uint4*)uvl)[t] = src[t];
  }

  // hT staging: thread t owns bytes [t*16, t*16+16) of each 8KB tile-PAIR.
  // Pair 0 (tiles 0,1) -> buf0 (rotated); regs hc0 = pair 1 (tiles 2,3, raw).
  const unsigned short* hTb = hT + (size_t)b * kN * kH;
  const char* hTc = (const char*)hTb;
  *(uint4*)(hbase + pi) = *(const uint4*)(hTc + t * 16);
  uint4 hc0 = *(const uint4*)(hTc + 8192 + t * 16);
  uint4 hn0 = {};

  // bits: PACK = JIT from adj; packer lane (brow 0..63, bh, bq4) covers word
  // 2*it + bh, byte bq4 of its row. else: stage all from global.
  const int brow = t >> 3;
  const int bc = t & 7;
  const int bh = bc >> 2;
  const int bq4 = bc & 3;
  const int* adjLp = adj + ((size_t)b * kN + row0 + brow) * kN + bh * 32 + bq4 * 8;
  uint4 qcA = {}, qcB = {}, qnA = {}, qnB = {};
  if (PACK) {
    const uint4 a0 = *(const uint4*)(adjLp);
    const uint4 a1 = *(const uint4*)(adjLp + 4);
    ((unsigned char*)blw)[(brow * 65 + bh) * 4 + bq4] = (unsigned char)pack8(a0, a1);  // words 0,1
    qcA = *(const uint4*)(adjLp + 64);   // words 2,3
    qcB = *(const uint4*)(adjLp + 68);
  } else {
#pragma unroll
    for (int ii = 0; ii < 8; ++ii) {
      const int idx = ii * 512 + t;   // 4096 words
      const int rr2 = idx >> 6, wj = idx & 63;
      blw[rr2 * 65 + wj] = bits[((size_t)b * kN + row0 + rr2) * 64 + wj];
    }
  }

  const float Ri = Rr[(size_t)b * kN + row0 + rloc];
  __syncthreads();

  // data-derived loop bound + row-activity (exact: zero uv word -> afrag = 0)
  {
    int lm = -1;
#pragma unroll
    for (int i = 0; i < 4; ++i)
      if (uvl[t * 4 + i] != 0u) lm = t * 4 + i;
    if (lm >= 0) atomicMax(mxp, lm);
    if (t < 64 && mask[(size_t)b * kN + row0 + t] != 0.0f) atomicOr(rfp, 1);
  }
  __syncthreads();
  const int mxv = *mxp;
  const int ntj = (mxv < 0) ? 0 : ((mxv >> 6) + 1);  // 64 cols per iter
  const bool ract = (*rfp != 0);

  f32x4 acc0 = {0.f, 0.f, 0.f, 0.f}, acc1 = {0.f, 0.f, 0.f, 0.f};
  f32x4 acc2 = {0.f, 0.f, 0.f, 0.f}, acc3 = {0.f, 0.f, 0.f, 0.f};
  f32x4 accz = {0.f, 0.f, 0.f, 0.f};
  s16x8 ones;
#pragma unroll
  for (int e = 0; e < 8; ++e) ones[e] = (r == 0) ? (short)0x3F80 : (short)0;

  if (ract) {
    // read-side rotated slot for this lane's row r
    const int rs = ((g + (r >> 1)) & 3) * 8;   // slot offset in shorts
    for (int jt = 0; jt < ntj; ++jt) {
      // issue loads for iter jt+1's publish: tile-pair jt+2; adj words 2jt+4,5
      if (jt < ntj - 2) {
        hn0 = *(const uint4*)(hTc + (size_t)(jt + 2) * 8192 + t * 16);
        if (PACK) {
          qnA = *(const uint4*)(adjLp + (size_t)(jt + 2) * 64);
          qnB = *(const uint4*)(adjLp + (size_t)(jt + 2) * 64 + 4);
        }
      }
      // publish for iter jt+1: tile-pair jt+1 (regs loaded at jt-1); words 2jt+2,3
      if (jt < ntj - 1) {
        *(uint4*)(hbase + ((jt + 1) & 1) * 4096 + pi) = hc0;
        if (PACK)
          ((unsigned char*)blw)[(brow * 65 + 2 * jt + 2 + bh) * 4 + bq4] =
              (unsigned char)pack8(qcA, qcB);
      }

      // consume chunk 2*jt + hf2 for rows rt*16..+16
      const unsigned int bw = blw[rloc * 65 + 2 * jt + hf2];
      const unsigned int byt = (bw >> (g * 8)) & 0xffu;
      const unsigned int* uvp = uvl + (2 * jt + hf2) * 32 + g * 8;
      const uint4 ua = *(const uint4*)uvp;
      const uint4 ub = *(const uint4*)(uvp + 4);
      union { s16x8 v; unsigned int w[4]; } afu;
      {
        const unsigned int uvw[8] = {ua.x, ua.y, ua.z, ua.w, ub.x, ub.y, ub.z, ub.w};
#pragma unroll
        for (int p = 0; p < 4; ++p) {
          unsigned int ulb = uvw[2 * p] & 0xFFFF0000u, vlb = uvw[2 * p] << 16;
          unsigned int uhb = uvw[2 * p + 1] & 0xFFFF0000u, vhb = uvw[2 * p + 1] << 16;
          float ulf, vlf, uhf, vhf;
          __builtin_memcpy(&ulf, &ulb, 4); __builtin_memcpy(&vlf, &vlb, 4);
          __builtin_memcpy(&uhf, &uhb, 4); __builtin_memcpy(&vhf, &vhb, 4);
          const float vall = fmaxf(ulf, Ri * vlf);
          const float valh = fmaxf(uhf, Ri * vhf);
          unsigned int lbits, hbits;
          __builtin_memcpy(&lbits, &vall, 4); __builtin_memcpy(&hbits, &valh, 4);
          lbits = (byt & (1u << (2 * p))) ? lbits : 0u;
          hbits = (byt & (1u << (2 * p + 1))) ? hbits : 0u;
          afu.w[p] = (hbits & 0xFFFF0000u) | (lbits >> 16);
        }
      }
      // rotated f reads: tile stride 2048, hg stride 512, row stride 32 (shorts)
      const unsigned short* cur = hbase + ((jt & 1) * 2 + hf2) * 2048 + r * 32 + rs;
      const s16x8 f0 = *(const s16x8*)(cur);
      const s16x8 f1 = *(const s16x8*)(cur + 512);
      const s16x8 f2 = *(const s16x8*)(cur + 1024);
      const s16x8 f3 = *(const s16x8*)(cur + 1536);

      acc0 = __builtin_amdgcn_mfma_f32_16x16x32_bf16(afu.v, f0, acc0, 0, 0, 0);
      acc1 = __builtin_amdgcn_mfma_f32_16x16x32_bf16(afu.v, f1, acc1, 0, 0, 0);
      acc2 = __builtin_amdgcn_mfma_f32_16x16x32_bf16(afu.v, f2, acc2, 0, 0, 0);
      acc3 = __builtin_amdgcn_mfma_f32_16x16x32_bf16(afu.v, f3, acc3, 0, 0, 0);
      accz = __builtin_amdgcn_mfma_f32_16x16x32_bf16(afu.v, ones, accz, 0, 0, 0);

      // raw barrier: wait LDS ops only; global prefetch stays in flight (T4)
      asm volatile("s_waitcnt lgkmcnt(0)" ::: "memory");
      __builtin_amdgcn_s_barrier();
      hc0 = hn0;
      if (PACK) { qcA = qnA; qcB = qnB; }
    }
  }

  // ---- epilogue: in-block combine of the two chunk-parity halves ----
  float* psumF = (float*)(smem + 24832);          // [64][66]
  float* zsumF = (float*)(smem + 41728);          // [64]
  if (hf2 == 1) {
#pragma unroll
    for (int q = 0; q < 4; ++q) {
      const int lrow = rt * 16 + g * 4 + q;
      psumF[lrow * 66 + r + 0]  = acc0[q];
      psumF[lrow * 66 + r + 16] = acc1[q];
      psumF[lrow * 66 + r + 32] = acc2[q];
      psumF[lrow * 66 + r + 48] = acc3[q];
      if (r == 0) zsumF[lrow] = accz[q];
    }
  }
  // PACK bits write-out MUST precede lhFF writes (lhFF overlaps uvl+blw start).
  if (PACK) {
#pragma unroll
    for (int ii = 0; ii < 8; ++ii) {
      const int idx = ii * 512 + t;
      const int rr2 = idx >> 6, wj = idx & 63;
      bits[((size_t)b * kN + row0 + rr2) * 64 + wj] = blw[rr2 * 65 + wj];
    }
  }
  __syncthreads();
  float* lhFF = (float*)smem;  // final h-layer rows [64][65] (TAIL and EMB)
  if (hf2 == 0) {
#pragma unroll
    for (int q = 0; q < 4; ++q) {
      const int lrow = rt * 16 + g * 4 + q;
      const float zq = __shfl(accz[q], (l & 48)) + zsumF[lrow];
      const float inv = (zq > 0.0f) ? 1.0f / zq : 0.0f;
      const size_t rowg = (size_t)b * kN + row0 + lrow;
      const float mk = mask[rowg];
      const float* hrp = hres + rowg * kH;
      const float o0 = eluf(fmaf(acc0[q] + psumF[lrow * 66 + r + 0],  inv, hrp[r + 0]))  * mk;
      const float o1 = eluf(fmaf(acc1[q] + psumF[lrow * 66 + r + 16], inv, hrp[r + 16])) * mk;
      const float o2 = eluf(fmaf(acc2[q] + psumF[lrow * 66 + r + 32], inv, hrp[r + 32])) * mk;
      const float o3 = eluf(fmaf(acc3[q] + psumF[lrow * 66 + r + 48], inv, hrp[r + 48])) * mk;
      lhFF[lrow * 65 + r + 0]  = o0;
      lhFF[lrow * 65 + r + 16] = o1;
      lhFF[lrow * 65 + r + 32] = o2;
      lhFF[lrow * 65 + r + 48] = o3;
    }
  }

  if (EMB) {
    // layer-2 embed for this block's 64 rows: h2 = lhFF(64x64) @ W2(64x64).
    // Wave (rt,hf2): rows rt*16..+16, cols hf2*32..+32 (ntb = hf2*2, +1).
    __syncthreads();
    const int ntb = hf2 * 2;
    s16x8 ah[2], al[2];
    {
      const float* arow = lhFF + (rt * 16 + r) * 65;
#pragma unroll
      for (int ks = 0; ks < 2; ++ks) {
#pragma unroll
        for (int j = 0; j < 8; ++j) {
          const float v = arow[ks * 32 + g * 8 + j];
          const unsigned short hh = f2bf(v);
          ah[ks][j] = (short)hh;
          al[ks][j] = (short)f2bf(v - bf2f(hh));
        }
      }
    }
    f32x4 e0 = {0.f, 0.f, 0.f, 0.f}, e1 = {0.f, 0.f, 0.f, 0.f};
#pragma unroll
    for (int ks = 0; ks < 2; ++ks) {
      const int kof = ks * 32 + g * 8;
      {
        const s16x8 bhi = *(const s16x8*)(w2thi + (ntb * 16 + r) * 64 + kof);
        const s16x8 blo = *(const s16x8*)(w2tlo + (ntb * 16 + r) * 64 + kof);
        e0 = __builtin_amdgcn_mfma_f32_16x16x32_bf16(ah[ks], bhi, e0, 0, 0, 0);
        e0 = __builtin_amdgcn_mfma_f32_16x16x32_bf16(al[ks], bhi, e0, 0, 0, 0);
        e0 = __builtin_amdgcn_mfma_f32_16x16x32_bf16(ah[ks], blo, e0, 0, 0, 0);
      }
      {
        const s16x8 bhi = *(const s16x8*)(w2thi + ((ntb + 1) * 16 + r) * 64 + kof);
        const s16x8 blo = *(const s16x8*)(w2tlo + ((ntb + 1) * 16 + r) * 64 + kof);
        e1 = __builtin_amdgcn_mfma_f32_16x16x32_bf16(ah[ks], bhi, e1, 0, 0, 0);
        e1 = __builtin_amdgcn_mfma_f32_16x16x32_bf16(al[ks], bhi, e1, 0, 0, 0);
        e1 = __builtin_amdgcn_mfma_f32_16x16x32_bf16(ah[ks], blo, e1, 0, 0, 0);
      }
    }
    float* lh2F = (float*)(smem + 24832);  // [64][66], reuse psum area
#pragma unroll
    for (int q = 0; q < 4; ++q) {
      const int lrow = rt * 16 + g * 4 + q;
      lh2F[lrow * 66 + ntb * 16 + r] = e0[q];
      lh2F[lrow * 66 + (ntb + 1) * 16 + r] = e1[q];
      const size_t rowg = (size_t)b * kN + row0 + lrow;
      h2res[rowg * kH + ntb * 16 + r] = e0[q];
      h2res[rowg * kH + (ntb + 1) * 16 + r] = e1[q];
    }
    __syncthreads();
    // hT2: 2 chunks (rb*2, rb*2+1), [chunk][col][row32]
    {
      const int ch = t >> 8;          // 0,1
      const int tt = t & 255;
      const int kr = tt & 31, wc = tt >> 5;
      const size_t tb2 = (size_t)b * kN * kH + (size_t)(rb * 2 + ch) * 2048;
#pragma unroll
      for (int it = 0; it < 8; ++it) {
        const int c = wc * 8 + it;
        hT2[tb2 + c * 32 + kr] = f2bf(lh2F[(ch * 32 + kr) * 66 + c]);
      }
    }
    // uvpk2 / Rr2: per row dot with asrc2/adst2 (8 lanes per row, 64 rows)
    {
      const int rw = t >> 3, c0 = (t & 7) * 8;
      float sp = 0.0f, dp = 0.0f;
#pragma unroll
      for (int j = 0; j < 8; ++j) {
        const float hv = lh2F[rw * 66 + c0 + j];
        sp = fmaf(hv, asrc2[c0 + j], sp);
        dp = fmaf(hv, adst2[c0 + j], dp);
      }
#pragma unroll
      for (int o = 4; o; o >>= 1) {
        sp += __shfl_xor(sp, o);
        dp += __shfl_xor(dp, o);
      }
      if ((t & 7) == 0) {
        const size_t rowg = (size_t)b * kN + row0 + rw;
        const bool mv = mask[rowg] != 0.0f;
        const float u = mv ? __expf(dp) : 0.0f;
        const float v = mv ? __expf(0.2f * dp) : 0.0f;
        uv2[rowg] = ((unsigned int)f2bf(u) << 16) | f2bf(v);
        Rr2[rowg] = __expf(-0.8f * sp);
      }
    }
  }

  if (TAIL) {
    __syncthreads();
    const int ln = t & 31;
    const int grp = t >> 5;   // 0..15, 4 rows each = 64
#pragma unroll
    for (int rr2 = 0; rr2 < 4; ++rr2) {
      const int lrow = grp * 4 + rr2;
      float accA = ab1[ln];
#pragma unroll 8
      for (int m = 0; m < kH; ++m) accA = fmaf(lhFF[lrow * 65 + m], aw1[m * 32 + ln], accA);
      float p = eluf(accA) * aw2[ln];
#pragma unroll
      for (int o = 16; o; o >>= 1) p += __shfl_xor(p, o, 32);
      if (ln == 0) logits[(size_t)b * kN + row0 + lrow] = p + ab2[0];
    }
    float cs = 0.0f;
    const int kcol = t & 63;
    const int seg = t >> 6;   // 0..7, 8 rows each
#pragma unroll
    for (int ii = 0; ii < 8; ++ii) cs += lhFF[(seg * 8 + ii) * 65 + kcol];
    float* csF = (float*)(smem + 41984);   // [8][64]
    csF[seg * 64 + kcol] = cs;
    __syncthreads();
    if (t < 64) {
      float s = 0.0f;
#pragma unroll
      for (int k2 = 0; k2 < 8; ++k2) s += csF[k2 * 64 + t];
      atomicAdd(&sumh[b * 64 + t], s);
    }
  }
}

// ---------------------------------------------------------------- critic head
__global__ __launch_bounds__(64) void k_critic2(
    const float* __restrict__ sumh, const float* __restrict__ mask,
    const float* __restrict__ cw1, const float* __restrict__ cb1,
    const float* __restrict__ cw2, const float* __restrict__ cb2,
    float* __restrict__ value) {
  __shared__ float lgh[64];
  const int b = blockIdx.x, t = threadIdx.x;
  float c = 0.0f;
#pragma unroll
  for (int ii = 0; ii < 32; ++ii) c += mask[(size_t)b * kN + t + 64 * ii];
#pragma unroll
  for (int off = 32; off; off >>= 1) c += __shfl_xor(c, off);
  lgh[t] = sumh[b * 64 + t] / fmaxf(c, 1.0f);
  __syncthreads();
  if (t < 32) {
    float acc = cb1[t];
#pragma unroll 8
    for (int m = 0; m < kH; ++m) acc = fmaf(lgh[m], cw1[m * 32 + t], acc);
    float p = eluf(acc) * cw2[t];
#pragma unroll
    for (int off = 16; off; off >>= 1) p += __shfl_xor(p, off, 32);
    if (t == 0) value[b] = p + cb2[0];
  }
}

// ----------------------------------------------------------------
extern "C" void kernel_launch(void* const* d_in, const int* in_sizes, int n_in,
                              void* d_out, int out_size, void* d_ws, size_t ws_size,
                              hipStream_t stream) {
  const float* x = (const float*)d_in[0];
  const int* adj = (const int*)d_in[1];
  const float* mask = (const float*)d_in[2];
  const float* W1 = (const float*)d_in[3];
  const float* asrc1 = (const float*)d_in[4];
  const float* adst1 = (const float*)d_in[5];
  const float* W2 = (const float*)d_in[6];
  const float* asrc2 = (const float*)d_in[7];
  const float* adst2 = (const float*)d_in[8];
  const float* aw1 = (const float*)d_in[9];
  const float* ab1 = (const float*)d_in[10];
  const float* aw2 = (const float*)d_in[11];
  const float* ab2 = (const float*)d_in[12];
  const float* cw1 = (const float*)d_in[13];
  const float* cb1 = (const float*)d_in[14];
  const float* cw2 = (const float*)d_in[15];
  const float* cb2 = (const float*)d_in[16];
  float* logits = (float*)d_out;
  float* value = (float*)d_out + kB * kN;

  char* ws = (char*)d_ws;
  size_t off = 0;
  auto take = [&](size_t bytes) {
    char* p = ws + off;
    off = (off + bytes + 255) & ~(size_t)255;
    return p;
  };
  unsigned int* bits = (unsigned int*)take((size_t)kB * kN * (kN / 8));
  float* hA = (float*)take((size_t)kB * kN * kH * 4);    // layer1 embed h (residual 1)
  float* hA2 = (float*)take((size_t)kB * kN * kH * 4);   // layer2 embed h (residual 2)
  unsigned short* hT1 = (unsigned short*)take((size_t)kB * kN * kH * 2);
  unsigned short* hT2 = (unsigned short*)take((size_t)kB * kN * kH * 2);
  unsigned int* uv1 = (unsigned int*)take((size_t)kB * kN * 4);
  unsigned int* uv2 = (unsigned int*)take((size_t)kB * kN * 4);
  float* R1 = (float*)take((size_t)kB * kN * 4);
  float* R2 = (float*)take((size_t)kB * kN * 4);
  float* sumh = (float*)take(kB * kH * 4);
  unsigned short* w2thi = (unsigned short*)take(64 * 64 * 2);
  unsigned short* w2tlo = (unsigned short*)take(64 * 64 * 2);

  // layer 1 embed (+ sumh zero, W2^T bf16 precompute)
  k_embed<<<kB * kN / 64, 256, 0, stream>>>(x, W1, asrc1, adst1, mask, hA, hT1, uv1, R1,
                                            sumh, W2, w2thi, w2tlo);
  // layer 1 attn, fused with layer 2 embed (writes hA2/hT2/uv2/R2; JIT-packs adj -> bits)
  k_attn<true, false, true><<<kB * 32, 512, 0, stream>>>(
      adj, bits, hT1, uv1, R1, hA, mask, aw1, ab1, aw2, ab2, logits, sumh,
      w2thi, w2tlo, asrc2, adst2, hA2, hT2, uv2, R2);
  // layer 2 attn, tail-fused (actor head + column sums)
  k_attn<false, true, false><<<kB * 32, 512, 0, stream>>>(
      adj, bits, hT2, uv2, R2, hA2, mask, aw1, ab1, aw2, ab2, logits, sumh,
      nullptr, nullptr, nullptr, nullptr, nullptr, nullptr, nullptr, nullptr);
  // critic
  k_critic2<<<kB, 64, 0, stream>>>(sumh, mask, cw1, cb1, cw2, cb2, value);
}